// Round 1
// baseline (2961.976 us; speedup 1.0000x reference)
//
#include <hip/hip_runtime.h>
#include <stdint.h>

typedef unsigned int u32;
typedef unsigned short u16;
typedef __attribute__((ext_vector_type(8))) short bf16x8;
typedef __attribute__((ext_vector_type(4))) float f32x4;

#define NTOK 32768
#define DDIM 1024
#define HDIM 4096
#define NEXP 8
#define MAXSLOTS 66560  // 65536 + 8*128 worst-case padded slots

__device__ __forceinline__ u16 f2bf(float f) {
  u32 u = __builtin_bit_cast(u32, f);
  u = (u + 0x7fff + ((u >> 16) & 1)) >> 16;   // round-to-nearest-even
  return (u16)u;
}

__device__ __forceinline__ void gload16(const void* g, void* l) {
  __builtin_amdgcn_global_load_lds((const __attribute__((address_space(1))) u32*)g,
                                   (__attribute__((address_space(3))) u32*)l, 16, 0, 0);
}

// ---------------- x fp32 -> bf16 ----------------
__global__ __launch_bounds__(256)
void k_cvt_x(const float* __restrict__ x, u16* __restrict__ xb, int n4) {
  int i = blockIdx.x * 256 + threadIdx.x;
  int stride = gridDim.x * 256;
  for (; i < n4; i += stride) {
    float4 v = ((const float4*)x)[i];
    u32 p0 = (u32)f2bf(v.x) | ((u32)f2bf(v.y) << 16);
    u32 p1 = (u32)f2bf(v.z) | ((u32)f2bf(v.w) << 16);
    ((uint2*)xb)[i] = make_uint2(p0, p1);
  }
}

// ------- W [E][R][C] fp32 -> WT [E][C][R] bf16 (tiled transpose) -------
__global__ __launch_bounds__(256)
void k_transpose(const float* __restrict__ W, u16* __restrict__ WT, int R, int C) {
  __shared__ float tile[64][65];
  int tilesC = C >> 6;
  int tilesPerE = (R >> 6) * tilesC;
  int b = blockIdx.x;
  int e = b / tilesPerE;
  int rem = b % tilesPerE;
  int tr = rem / tilesC, tc = rem % tilesC;
  const float* src = W + (size_t)e * R * C + (size_t)(tr * 64) * C + tc * 64;
  int tid = threadIdx.x;
#pragma unroll
  for (int it = 0; it < 16; it++) {
    int idx = it * 256 + tid;
    int r = idx >> 6, c = idx & 63;
    tile[r][c] = src[(size_t)r * C + c];
  }
  __syncthreads();
  u16* dst = WT + (size_t)e * R * C + (size_t)(tc * 64) * R + tr * 64;
#pragma unroll
  for (int it = 0; it < 16; it++) {
    int idx = it * 256 + tid;
    int cc = idx >> 6, rr = idx & 63;
    dst[(size_t)cc * R + rr] = f2bf(tile[rr][cc]);
  }
}

// ---------------- router: fp32 logits, top-2, weights ----------------
__global__ __launch_bounds__(128)
void k_router(const float* __restrict__ x, const float* __restrict__ Wr,
              const float* __restrict__ br, int* __restrict__ tokPack,
              float* __restrict__ tokW, int* __restrict__ counts) {
  __shared__ float wl[DDIM * NEXP];
  int tid = threadIdx.x;
  for (int i = tid; i < DDIM * NEXP; i += 128) wl[i] = Wr[i];
  __syncthreads();
  int n = blockIdx.x * 128 + tid;
  float acc[8];
#pragma unroll
  for (int e = 0; e < 8; e++) acc[e] = br[e];
  const float4* xr = (const float4*)(x + (size_t)n * DDIM);
  const float4* wlv = (const float4*)wl;
  for (int d4 = 0; d4 < 256; d4++) {
    float4 xv = xr[d4];
#pragma unroll
    for (int j = 0; j < 4; j++) {
      float xs = (&xv.x)[j];
      float4 wa = wlv[(d4 * 4 + j) * 2 + 0];
      float4 wb = wlv[(d4 * 4 + j) * 2 + 1];
      acc[0] += xs * wa.x; acc[1] += xs * wa.y; acc[2] += xs * wa.z; acc[3] += xs * wa.w;
      acc[4] += xs * wb.x; acc[5] += xs * wb.y; acc[6] += xs * wb.z; acc[7] += xs * wb.w;
    }
  }
  float v0 = -3.0e38f, v1 = -3.0e38f;
  int i0 = 0, i1 = 0;
#pragma unroll
  for (int e = 0; e < 8; e++) {
    float v = acc[e];
    if (v > v0) { v1 = v0; i1 = i0; v0 = v; i0 = e; }
    else if (v > v1) { v1 = v; i1 = e; }
  }
  float w0 = 1.0f / (1.0f + expf(v1 - v0));
  tokPack[n] = i0 | (i1 << 8);
  tokW[n] = w0;
  atomicAdd(&counts[i0], 1);
  atomicAdd(&counts[i1], 1);
}

// sched layout (ints): [0..7]=counts, [8..16]=padOff (padOff[8]=totalPadded), [17..24]=cursors
__global__ void k_sched(int* __restrict__ sched) {
  if (threadIdx.x == 0 && blockIdx.x == 0) {
    int* padOff = sched + 8;
    int acc = 0;
    for (int e = 0; e < 8; e++) {
      padOff[e] = acc;
      int c = sched[e];
      acc += ((c + 127) >> 7) << 7;
    }
    padOff[8] = acc;
  }
}

__global__ __launch_bounds__(256)
void k_scatter(const int* __restrict__ tokPack, const float* __restrict__ tokW,
               int* __restrict__ sched, int* __restrict__ slotTok,
               float* __restrict__ slotW) {
  int n = blockIdx.x * 256 + threadIdx.x;
  int p = tokPack[n];
  float w0 = tokW[n];
  int e0 = p & 255, e1 = p >> 8;
  const int* padOff = sched + 8;
  int* cursors = sched + 17;
  int s0 = padOff[e0] + atomicAdd(&cursors[e0], 1);
  slotTok[s0] = n; slotW[s0] = w0;
  int s1 = padOff[e1] + atomicAdd(&cursors[e1], 1);
  slotTok[s1] = n; slotW[s1] = 1.0f - w0;
}

// ---------------- grouped GEMM (up: UP=true, down: UP=false) ----------------
// 128x128 tile, BK=64, 4 waves (2x2 of 64x64), mfma 16x16x32 bf16, 2-phase prefetch.
template<bool UP>
__global__ __launch_bounds__(256, 2)
void k_gemm(const u16* __restrict__ A, const u16* __restrict__ Bw,
            const float* __restrict__ bias, const int* __restrict__ slotTok,
            const float* __restrict__ slotW, const int* __restrict__ sched,
            u16* __restrict__ Hbuf, float* __restrict__ dout, int chunkBase) {
  constexpr int KLEN = UP ? DDIM : HDIM;   // A/B row length (k)
  constexpr int NLEN = UP ? HDIM : DDIM;   // output cols per expert
  constexpr int NT = NLEN / 128;
  constexpr int NK = KLEN / 64;
  const int* padOff = sched + 8;
  const int totalPadded = padOff[8];
  const int wg = blockIdx.x;
  const int mLocal = wg / NT;
  const int nt = wg % NT;
  const int rowbase = chunkBase + mLocal * 128;
  if (rowbase >= totalPadded) return;
  int e = 0;
#pragma unroll
  for (int i = 0; i < NEXP; i++)
    if (rowbase >= padOff[i + 1]) e = i + 1;
  const int n0 = nt * 128;
  const u16* Be = Bw + (size_t)e * HDIM * DDIM + (size_t)n0 * KLEN;
  const int tid = threadIdx.x, lane = tid & 63, wid = tid >> 6;
  const int localBase = rowbase - chunkBase;
  __shared__ u16 As[2][128 * 64];
  __shared__ u16 Bs[2][128 * 64];
  const char* aSrc[4];
  const char* bSrc[4];
#pragma unroll
  for (int i = 0; i < 4; i++) {
    const int r = 8 * (i * 4 + wid) + (lane >> 3);
    if constexpr (UP) {
      const int tok = slotTok[rowbase + r];
      aSrc[i] = (const char*)(A + (size_t)tok * KLEN) + (lane & 7) * 16;
    } else {
      aSrc[i] = (const char*)(A + (size_t)(localBase + r) * KLEN) + (lane & 7) * 16;
    }
    bSrc[i] = (const char*)(Be + (size_t)r * KLEN) + (lane & 7) * 16;
  }
  const int wr = wid >> 1, wc = wid & 1;
  const int aBase = (wr * 64 + (lane & 15)) * 64 + (lane >> 4) * 8;
  const int bBase = (wc * 64 + (lane & 15)) * 64 + (lane >> 4) * 8;
  f32x4 acc[4][4] = {};

#define STAGEK(buf, kt)                                                        \
  {                                                                            \
    const size_t koff = (size_t)(kt) * 128;                                    \
    _Pragma("unroll") for (int i = 0; i < 4; i++)                              \
        gload16(aSrc[i] + koff, &As[buf][(i * 4 + wid) * 512]);                \
    _Pragma("unroll") for (int i = 0; i < 4; i++)                              \
        gload16(bSrc[i] + koff, &Bs[buf][(i * 4 + wid) * 512]);                \
  }
#define COMPUTEK(buf)                                                          \
  {                                                                            \
    const u16* Ab = &As[buf][0];                                               \
    const u16* Bb = &Bs[buf][0];                                               \
    _Pragma("unroll") for (int kk = 0; kk < 2; kk++) {                         \
      bf16x8 af[4], bfr[4];                                                    \
      _Pragma("unroll") for (int mi = 0; mi < 4; mi++)                         \
          af[mi] = *(const bf16x8*)(Ab + aBase + mi * 1024 + kk * 32);         \
      _Pragma("unroll") for (int ni = 0; ni < 4; ni++)                         \
          bfr[ni] = *(const bf16x8*)(Bb + bBase + ni * 1024 + kk * 32);        \
      _Pragma("unroll") for (int mi = 0; mi < 4; mi++) {                       \
        _Pragma("unroll") for (int ni = 0; ni < 4; ni++)                       \
            acc[mi][ni] = __builtin_amdgcn_mfma_f32_16x16x32_bf16(             \
                af[mi], bfr[ni], acc[mi][ni], 0, 0, 0);                        \
      }                                                                        \
    }                                                                          \
  }

  STAGEK(0, 0);
  __syncthreads();
#pragma unroll 1
  for (int kt = 0; kt < NK; kt += 2) {
    if (kt + 1 < NK) STAGEK(1, kt + 1);
    COMPUTEK(0);
    __syncthreads();
    if (kt + 2 < NK) STAGEK(0, kt + 2);
    COMPUTEK(1);
    __syncthreads();
  }

  if constexpr (UP) {
    // silu(acc + b1) -> Hbuf bf16
#pragma unroll
    for (int ni = 0; ni < 4; ni++) {
      const int col = n0 + wc * 64 + ni * 16 + (lane & 15);
      const float bv = bias[e * HDIM + col];
#pragma unroll
      for (int mi = 0; mi < 4; mi++) {
        const int rowb = localBase + wr * 64 + mi * 16 + (lane >> 4) * 4;
#pragma unroll
        for (int r = 0; r < 4; r++) {
          float v = acc[mi][ni][r] + bv;
          float s = v / (1.0f + __expf(-v));
          Hbuf[(size_t)(rowb + r) * HDIM + col] = f2bf(s);
        }
      }
    }
  } else {
    // w * (acc + b2) -> atomicAdd into out (exactly 2 adds per element)
#pragma unroll
    for (int mi = 0; mi < 4; mi++) {
#pragma unroll
      for (int r = 0; r < 4; r++) {
        const int prow = rowbase + wr * 64 + mi * 16 + (lane >> 4) * 4 + r;
        const float w = slotW[prow];
        const int tok = slotTok[prow];
        if (w != 0.0f) {
#pragma unroll
          for (int ni = 0; ni < 4; ni++) {
            const int col = n0 + wc * 64 + ni * 16 + (lane & 15);
            const float y = acc[mi][ni][r] + bias[e * DDIM + col];
            atomicAdd(dout + (size_t)tok * DDIM + col, w * y);
          }
        }
      }
    }
  }
#undef STAGEK
#undef COMPUTEK
}

// ---------------- residual gate + LayerNorm (in place on out) ----------------
__global__ __launch_bounds__(256)
void k_ln(const float* __restrict__ x, const float* __restrict__ gs,
          const float* __restrict__ gamma, const float* __restrict__ beta,
          float* __restrict__ out) {
  const int row = blockIdx.x, tid = threadIdx.x;
  const float g = gs[0];
  const float4* xr = (const float4*)(x + (size_t)row * DDIM);
  float4* orow = (float4*)(out + (size_t)row * DDIM);
  float4 xv = xr[tid];
  float4 av = orow[tid];
  float4 z;
  z.x = xv.x + g * av.x; z.y = xv.y + g * av.y;
  z.z = xv.z + g * av.z; z.w = xv.w + g * av.w;
  float s = z.x + z.y + z.z + z.w;
  float ss = z.x * z.x + z.y * z.y + z.z * z.z + z.w * z.w;
#pragma unroll
  for (int m = 1; m < 64; m <<= 1) {
    s += __shfl_xor(s, m);
    ss += __shfl_xor(ss, m);
  }
  __shared__ float sh[8];
  if ((tid & 63) == 0) {
    sh[(tid >> 6) * 2] = s;
    sh[(tid >> 6) * 2 + 1] = ss;
  }
  __syncthreads();
  s = sh[0] + sh[2] + sh[4] + sh[6];
  ss = sh[1] + sh[3] + sh[5] + sh[7];
  const float mu = s * (1.0f / 1024.0f);
  const float var = ss * (1.0f / 1024.0f) - mu * mu;
  const float rstd = rsqrtf(var + 1e-5f);
  float4 gm = ((const float4*)gamma)[tid];
  float4 bt = ((const float4*)beta)[tid];
  float4 o;
  o.x = (z.x - mu) * rstd * gm.x + bt.x;
  o.y = (z.y - mu) * rstd * gm.y + bt.y;
  o.z = (z.z - mu) * rstd * gm.z + bt.z;
  o.w = (z.w - mu) * rstd * gm.w + bt.w;
  orow[tid] = o;
}

extern "C" void kernel_launch(void* const* d_in, const int* in_sizes, int n_in,
                              void* d_out, int out_size, void* d_ws, size_t ws_size,
                              hipStream_t stream) {
  const float* x = (const float*)d_in[0];
  const float* Wr = (const float*)d_in[1];
  const float* br = (const float*)d_in[2];
  const float* W1 = (const float*)d_in[3];
  const float* b1 = (const float*)d_in[4];
  const float* W2 = (const float*)d_in[5];
  const float* b2 = (const float*)d_in[6];
  const float* gs = (const float*)d_in[7];
  const float* gamma = (const float*)d_in[8];
  const float* beta = (const float*)d_in[9];
  float* out = (float*)d_out;

  char* ws = (char*)d_ws;
  size_t off = 0;
  auto alloc = [&](size_t bytes) -> void* {
    void* p = ws + off;
    off += (bytes + 255) / 256 * 256;
    return p;
  };
  u16* xb = (u16*)alloc((size_t)NTOK * DDIM * 2);
  u16* W1T = (u16*)alloc((size_t)NEXP * HDIM * DDIM * 2);
  u16* W2T = (u16*)alloc((size_t)NEXP * HDIM * DDIM * 2);
  int* tokPack = (int*)alloc((size_t)NTOK * 4);
  float* tokW = (float*)alloc((size_t)NTOK * 4);
  int* slotTok = (int*)alloc((size_t)MAXSLOTS * 4);
  float* slotW = (float*)alloc((size_t)MAXSLOTS * 4);
  int* sched = (int*)alloc(128 * 4);
  size_t fixed = off;
  size_t avail = ws_size > fixed ? ws_size - fixed : 0;
  long long chv = (long long)(avail / ((size_t)HDIM * 2));
  int CH = (int)(chv > MAXSLOTS ? MAXSLOTS : chv);
  CH = (CH / 128) * 128;
  if (CH < 128) CH = 128;  // best effort; requires ws_size >= ~203 MB
  u16* Hbuf = (u16*)alloc((size_t)CH * HDIM * 2);
  int nch = (MAXSLOTS + CH - 1) / CH;

  // zero the accumulator output and the slot/sched region (fresh every launch)
  hipMemsetAsync(d_out, 0, (size_t)out_size * 4, stream);
  hipMemsetAsync(slotTok, 0, (size_t)((char*)sched + 512 - (char*)slotTok), stream);

  k_cvt_x<<<2048, 256, 0, stream>>>(x, xb, NTOK * DDIM / 4);
  k_transpose<<<NEXP * (DDIM / 64) * (HDIM / 64), 256, 0, stream>>>(W1, W1T, DDIM, HDIM);
  k_transpose<<<NEXP * (HDIM / 64) * (DDIM / 64), 256, 0, stream>>>(W2, W2T, HDIM, DDIM);
  k_router<<<NTOK / 128, 128, 0, stream>>>(x, Wr, br, tokPack, tokW, sched);
  k_sched<<<1, 64, 0, stream>>>(sched);
  k_scatter<<<NTOK / 256, 256, 0, stream>>>(tokPack, tokW, sched, slotTok, slotW);
  for (int c = 0; c < nch; c++) {
    k_gemm<true><<<(CH / 128) * (HDIM / 128), 256, 0, stream>>>(
        xb, W1T, b1, slotTok, slotW, sched, Hbuf, out, c * CH);
    k_gemm<false><<<(CH / 128) * (DDIM / 128), 256, 0, stream>>>(
        Hbuf, W2T, b2, slotTok, slotW, sched, Hbuf, out, c * CH);
  }
  k_ln<<<NTOK, 256, 0, stream>>>(x, gs, gamma, beta, out);
}